// Round 8
// baseline (369.786 us; speedup 1.0000x reference)
//
#include <hip/hip_runtime.h>

#define B_ 4
#define T_ 1024
#define D_ 256
#define O_ 256
#define NC 32   // chunks along T
#define CL 32   // chunk length (NC*CL == T_)

#define TROWS 16            // W rows per LDS tile (16 KB)
#define NTILE (D_ / TROWS)  // 16 tiles per t

typedef float v4f __attribute__((ext_vector_type(4)));

// ---------------- Kernel A: per-chunk sums S[b,c,d] ----------------
__global__ __launch_bounds__(256) void chunk_sums(const float* __restrict__ x,
                                                  float* __restrict__ S) {
    const int d  = threadIdx.x;          // 0..255
    const int bc = blockIdx.x;           // b*NC + c
    const int b  = bc / NC;
    const int c  = bc % NC;
    const float* xp = x + ((size_t)b * T_ + (size_t)c * CL) * D_ + d;
    float s = 0.f;
#pragma unroll
    for (int i = 0; i < CL; ++i) s += xp[(size_t)i * D_];
    S[((size_t)b * NC + c) * D_ + d] = s;
}

// ---------------- Kernel B: cm[b,t,d] = cumsum(x)/(t+1) ----------------
__global__ __launch_bounds__(256) void cumsum_mean(const float* __restrict__ x,
                                                   const float* __restrict__ S,
                                                   float* __restrict__ cm) {
    const int d  = threadIdx.x;
    const int bc = blockIdx.x;
    const int b  = bc / NC;
    const int c  = bc % NC;
    float off = 0.f;
#pragma unroll
    for (int cc = 0; cc < NC; ++cc) {
        const float v = S[((size_t)b * NC + cc) * D_ + d];
        off += (cc < c) ? v : 0.f;
    }
    const float* xp = x  + ((size_t)b * T_ + (size_t)c * CL) * D_ + d;
    float*       cp = cm + ((size_t)b * T_ + (size_t)c * CL) * D_ + d;
    float run = off;
#pragma unroll 4
    for (int i = 0; i < CL; ++i) {
        run += xp[(size_t)i * D_];
        const int t = c * CL + i;
        cp[(size_t)i * D_] = run / (float)(t + 1);   // IEEE divide, matches ref
    }
}

// ---------------- Kernel C: out[b,t,:] = cm[b,t,:] @ W[t] ----------------
// DMA-staged variant: block = t, 4 waves, wave wv == batch index b.
// W[t] is streamed through LDS in 16-row (16 KB) tiles, double-buffered,
// staged with __builtin_amdgcn_global_load_lds width=16 (wave-uniform LDS row
// base + lane*16 auto; per-lane global src). Counted s_waitcnt vmcnt(4) + raw
// s_barrier keeps the next tile's 4 loads in flight across the barrier (no
// vmcnt(0) drain — the __syncthreads trap). Thread (b=wv, oq=lane) owns
// out[b][t][oq*4..+3] completely: no cross-wave reduction, no epilogue LDS.
// VGPR ~40, LDS 32 KB -> 5 blocks/CU, 20 waves/CU.
__global__ __launch_bounds__(256) void gemm_t(const float* __restrict__ cm,
                                              const float* __restrict__ W,
                                              float* __restrict__ out) {
    const int t    = blockIdx.x;                                   // 0..T_-1
    const int tid  = threadIdx.x;
    const int wv   = __builtin_amdgcn_readfirstlane(tid >> 6);     // wave = b
    const int lane = tid & 63;                                     // o-quad

    __shared__ float tile[2][TROWS][O_];   // 2 x 16 KB

    const float* Wt  = W  + (size_t)t * D_ * O_;
    const float* cmt = cm + ((size_t)wv * T_ + t) * D_;            // uniform

    // stage tile k: wave wv stages rows [k*16 + wv*4, +4); one width-16
    // global_load_lds per row (64 lanes x 16 B = 1 KB row).
    auto stage = [&](int k) {
#pragma unroll
        for (int j = 0; j < 4; ++j) {
            const float* g = Wt + ((size_t)k * TROWS + wv * 4 + j) * O_ + lane * 4;
            float*       l = &tile[k & 1][wv * 4 + j][0];          // row base
            __builtin_amdgcn_global_load_lds(
                (const __attribute__((address_space(1))) unsigned int*)g,
                (__attribute__((address_space(3))) unsigned int*)l,
                16, 0, 0);
        }
    };

    v4f acc = (v4f)(0.f);

    stage(0);
#pragma unroll 1
    for (int k = 0; k < NTILE; ++k) {
        if (k + 1 < NTILE) {
            stage(k + 1);                                  // 4 more in flight
            asm volatile("s_waitcnt vmcnt(4)" ::: "memory");  // tile k landed
        } else {
            asm volatile("s_waitcnt vmcnt(0)" ::: "memory");
        }
        __builtin_amdgcn_sched_barrier(0);
        __builtin_amdgcn_s_barrier();                      // all waves' rows in
        __builtin_amdgcn_sched_barrier(0);

        const float* cs = cmt + k * TROWS;                 // 16 uniform scalars
#pragma unroll
        for (int r = 0; r < TROWS; ++r) {
            const v4f w4 = *(const v4f*)&tile[k & 1][r][lane * 4];
            acc += cs[r] * w4;                             // v_fmac f32 x4
        }
        __builtin_amdgcn_s_barrier();                      // done with buf k&1
    }

    __builtin_nontemporal_store(
        acc, (v4f*)&out[((size_t)wv * T_ + t) * O_ + (size_t)lane * 4]);
}

extern "C" void kernel_launch(void* const* d_in, const int* in_sizes, int n_in,
                              void* d_out, int out_size, void* d_ws, size_t ws_size,
                              hipStream_t stream) {
    const float* x = (const float*)d_in[0];   // (B,T,D) f32
    const float* W = (const float*)d_in[1];   // (T,D,O) f32
    float* out = (float*)d_out;               // (B,T,O) f32

    float* cm = (float*)d_ws;                        // B*T*D floats = 4 MB
    float* S  = (float*)d_ws + (size_t)B_ * T_ * D_; // B*NC*D floats = 128 KB

    chunk_sums <<<B_ * NC, 256, 0, stream>>>(x, S);
    cumsum_mean<<<B_ * NC, 256, 0, stream>>>(x, S, cm);
    gemm_t     <<<T_,      256, 0, stream>>>(cm, W, out);
}